// Round 8
// baseline (645.177 us; speedup 1.0000x reference)
//
#include <hip/hip_runtime.h>
#include <stdint.h>

typedef __attribute__((ext_vector_type(4))) float f32x4;
typedef __attribute__((ext_vector_type(8))) short s16x8;
typedef unsigned long long u64;

#define CC   192
#define NN   16384
#define EE   4
#define HIDD 384

// chunking: 2048 tiles -> 4 chunks x 512 tiles (= 2 images each, tiles never
// straddle chunk): hid ws = 32768 tok x 4 e x 384 x 1B = 50.33 MB, L3-resident.
#define NCHUNK 4
#define TPC    512          // tiles per chunk

// ws layout (bytes)
#define WS_W1B   0          // w1 bf16    589824
#define WS_W2F8  589824     // w2 fp8     294912
#define WS_GATES 884736     // gates f32  524288 (32768 tok x 4)
#define WS_HID   1409024    // hid fp8    50331648
// total 51,740,672 B

__device__ __forceinline__ uint16_t bfbits(float f){
  uint32_t u = __builtin_bit_cast(uint32_t, f);
  u += 0x7FFFu + ((u >> 16) & 1u);
  return (uint16_t)(u >> 16);
}
__device__ __forceinline__ uint32_t pkbf(float lo, float hi){
  uint32_t ul = __builtin_bit_cast(uint32_t, lo);
  uint32_t uh = __builtin_bit_cast(uint32_t, hi);
  ul += 0x7FFFu + ((ul >> 16) & 1u);
  uh += 0x7FFFu + ((uh >> 16) & 1u);
  return (ul >> 16) | (uh & 0xFFFF0000u);
}
// tanh-form GELU, |err| <= ~3e-3 (threshold 0.109; measured absmax 0.031)
__device__ __forceinline__ float gelu_f(float v){
  float x2 = v * v;
  float z = v * __builtin_fmaf(x2, -0.1029432f, -2.3022082f);
  float e = __builtin_amdgcn_exp2f(z);
  return v * __builtin_amdgcn_rcpf(1.0f + e);
}
__device__ __forceinline__ f32x4 mfma16(s16x8 a, s16x8 b, f32x4 c){
  return __builtin_amdgcn_mfma_f32_16x16x32_bf16(a, b, c, 0, 0, 0);
}
// fp8 e4m3 GEMM (OCP e4m3fn on gfx950); same MFMA rate as bf16, half the bytes.
__device__ __forceinline__ f32x4 mfma8(u64 a, u64 b, f32x4 c){
  asm("v_mfma_f32_16x16x32_fp8_fp8 %0, %1, %2, %0" : "+v"(c) : "v"(a), "v"(b));
  return c;
}

// ---- f32 -> fp8 e4m3fn (RNE). HW packed convert if available, manual fallback.
#if __has_builtin(__builtin_amdgcn_cvt_pk_fp8_f32)
__device__ __forceinline__ uint32_t fp8x4(float a, float b, float c, float d){
  int v = __builtin_amdgcn_cvt_pk_fp8_f32(a, b, 0, false);   // low word
  v = __builtin_amdgcn_cvt_pk_fp8_f32(c, d, v, true);        // high word
  return (uint32_t)v;
}
#else
__device__ __forceinline__ uint32_t fp8b(float f){
  uint32_t u = __builtin_bit_cast(uint32_t, f);
  uint32_t s = (u >> 24) & 0x80u;
  float af = fminf(__builtin_fabsf(f), 448.0f);
  if (af < 0.015625f) return s;                 // FTZ (subnormal range, err<=2^-6)
  uint32_t v = __builtin_bit_cast(uint32_t, af);
  v += 0x7FFFFu + ((v >> 20) & 1u);             // RNE into 3-bit mantissa
  uint32_t e = (v >> 23) - 120u;                // bias 127 -> 7
  return s | (e << 3) | ((v >> 20) & 7u);
}
__device__ __forceinline__ uint32_t fp8x4(float a, float b, float c, float d){
  return fp8b(a) | (fp8b(b) << 8) | (fp8b(c) << 16) | (fp8b(d) << 24);
}
#endif

// weight convert: w1 -> bf16, w2 -> fp8 (294912 elements each)
extern "C" __global__ void kconv(const float* __restrict__ w1, const float* __restrict__ w2,
                                 uint16_t* __restrict__ w1b, uint8_t* __restrict__ w2f8){
  int i = blockIdx.x * 256 + threadIdx.x;
  w1b[i]  = bfbits(w1[i]);
  w2f8[i] = (uint8_t)(fp8x4(w2[i], 0.0f, 0.0f, 0.0f) & 0xFFu);
}

// ===================== K1: router + GEMM1 + GELU*gate -> fp8 hid =====================
// 1 block = 64 tokens, 4 waves split the 384 hid features (96 each).
// After the 2 router barriers the main loop has NO barriers (waves independent).
__global__ __launch_bounds__(256, 2) void k1(
    const float* __restrict__ x, const float* __restrict__ rw,
    const float* __restrict__ rb, const uint16_t* __restrict__ w1b,
    const float* __restrict__ b1, float* __restrict__ gws,
    uint8_t* __restrict__ hid, int c0)
{
  // LDS: [0,24576) X tile [64][192] bf16 swizzled; [24576,28672) partials; [28672,29696) gates
  __shared__ __align__(16) unsigned char S[29696];
  const int tid  = threadIdx.x;
  const int lane = tid & 63;
  const int wv   = tid >> 6;
  const int lq   = lane & 15;
  const int lg   = lane >> 4;
  const int lt   = blockIdx.x;          // tile within chunk
  const int tile = c0 * TPC + lt;
  const int b    = tile >> 8;
  const int n0   = (tile & 255) << 6;
  const float* xb = x + (size_t)b * CC * NN;

  // ---- Phase 1: stage X (bf16 swizzled) + fp32 router partials
  {
    const int t = lane;
    const uint32_t rowbp = (uint32_t)t * 384u;
    const uint32_t sw    = ((uint32_t)(t & 7)) << 4;
    float a0 = 0.f, a1 = 0.f, a2 = 0.f, a3 = 0.f;
    #pragma unroll 8
    for (int j = 0; j < 48; j += 2){
      const int c = wv * 48 + j;
      const float v0 = xb[(size_t)c * NN + n0 + t];
      const float v1 = xb[(size_t)(c + 1) * NN + n0 + t];
      a0 = __builtin_fmaf(v1, rw[c + 1],          __builtin_fmaf(v0, rw[c],          a0));
      a1 = __builtin_fmaf(v1, rw[CC + c + 1],     __builtin_fmaf(v0, rw[CC + c],     a1));
      a2 = __builtin_fmaf(v1, rw[2 * CC + c + 1], __builtin_fmaf(v0, rw[2 * CC + c], a2));
      a3 = __builtin_fmaf(v1, rw[3 * CC + c + 1], __builtin_fmaf(v0, rw[3 * CC + c], a3));
      *(uint32_t*)(S + rowbp + (((uint32_t)(2 * c)) ^ sw)) = pkbf(v0, v1);
    }
    float* pl = (float*)(S + 24576);
    pl[(wv * 4 + 0) * 64 + t] = a0;
    pl[(wv * 4 + 1) * 64 + t] = a1;
    pl[(wv * 4 + 2) * 64 + t] = a2;
    pl[(wv * 4 + 3) * 64 + t] = a3;
  }
  __syncthreads();

  // ---- Phase 2 (tid<64): router top-2 + softmax -> gates (LDS + global ws)
  if (tid < 64){
    const int t = tid;
    const float* pl = (const float*)(S + 24576);
    float l0 = rb[0], l1 = rb[1], l2 = rb[2], l3 = rb[3];
    #pragma unroll
    for (int cg = 0; cg < 4; ++cg){
      l0 += pl[(cg * 4 + 0) * 64 + t];
      l1 += pl[(cg * 4 + 1) * 64 + t];
      l2 += pl[(cg * 4 + 2) * 64 + t];
      l3 += pl[(cg * 4 + 3) * 64 + t];
    }
    int i1 = 0; float v1 = l0;
    if (l1 > v1){ v1 = l1; i1 = 1; }
    if (l2 > v1){ v1 = l2; i1 = 2; }
    if (l3 > v1){ v1 = l3; i1 = 3; }
    float v2 = -3.0e38f; int i2 = 0;
    if (i1 != 0){ v2 = l0; i2 = 0; }
    if (i1 != 1 && l1 > v2){ v2 = l1; i2 = 1; }
    if (i1 != 2 && l2 > v2){ v2 = l2; i2 = 2; }
    if (i1 != 3 && l3 > v2){ v2 = l3; i2 = 3; }
    const float ex = __expf(v2 - v1);
    const float ga = 1.0f / (1.0f + ex);
    const float gb = ex * ga;
    f32x4 g;
    g[0] = (i1 == 0) ? ga : ((i2 == 0) ? gb : 0.0f);
    g[1] = (i1 == 1) ? ga : ((i2 == 1) ? gb : 0.0f);
    g[2] = (i1 == 2) ? ga : ((i2 == 2) ? gb : 0.0f);
    g[3] = (i1 == 3) ? ga : ((i2 == 3) ? gb : 0.0f);
    *(f32x4*)(S + 28672 + t * 16) = g;
    *(f32x4*)(gws + ((size_t)lt * 64 + t) * 4) = g;
  }
  __syncthreads();   // X + gates settled; no more barriers

  const float* gl = (const float*)(S + 28672);
  const uint32_t xsw = ((uint32_t)(lq & 7)) << 4;
  uint32_t rowb[4];
  #pragma unroll
  for (int np = 0; np < 4; ++np) rowb[np] = (uint32_t)(16 * np + lq) * 384u;
  const uint16_t* w1t = w1b + (size_t)(wv * 96 + lq) * CC + 8 * lg;

  #pragma unroll 1
  for (int e = 0; e < EE; ++e){
    float gt[4];
    #pragma unroll
    for (int np = 0; np < 4; ++np) gt[np] = gl[(16 * np + lq) * 4 + e];
    // GEMM1: 96 feats x 64 tok per wave, bias-init
    f32x4 hacc[6][4];
    #pragma unroll
    for (int m = 0; m < 6; ++m){
      const f32x4 bv = *(const f32x4*)(b1 + e * HIDD + wv * 96 + 16 * m + 4 * lg);
      #pragma unroll
      for (int np = 0; np < 4; ++np) hacc[m][np] = bv;
    }
    const uint16_t* w1p = w1t + (size_t)e * HIDD * CC;
    #pragma unroll
    for (int kk = 0; kk < 6; ++kk){
      s16x8 wf[6], xk[4];
      #pragma unroll
      for (int m = 0; m < 6; ++m)
        wf[m] = *(const s16x8*)(w1p + (size_t)(16 * m) * CC + kk * 32);
      #pragma unroll
      for (int np = 0; np < 4; ++np)
        xk[np] = *(const s16x8*)(S + rowb[np] + (((uint32_t)(64 * kk + 16 * lg)) ^ xsw));
      #pragma unroll
      for (int np = 0; np < 4; ++np)
        #pragma unroll
        for (int m = 0; m < 6; ++m)
          hacc[m][np] = mfma16(wf[m], xk[np], hacc[m][np]);
    }
    // GELU * gate -> fp8 hid (u32 = 4 consecutive features per lane)
    #pragma unroll
    for (int np = 0; np < 4; ++np){
      uint8_t* hp = hid + ((size_t)((lt * 64 + 16 * np + lq) * 4 + e)) * 384
                        + wv * 96 + 4 * lg;
      const float g = gt[np];
      #pragma unroll
      for (int m = 0; m < 6; ++m){
        const uint32_t pk = fp8x4(gelu_f(hacc[m][np][0]) * g,
                                  gelu_f(hacc[m][np][1]) * g,
                                  gelu_f(hacc[m][np][2]) * g,
                                  gelu_f(hacc[m][np][3]) * g);
        *(uint32_t*)(hp + 16 * m) = pk;
      }
    }
  }
}

// ===================== K2: GEMM2 (fp8 x fp8) + bias + residual =====================
// 1 block = 64 tokens, 4 waves split 192 out-channels (48 each). Gates pre-folded
// into hid, so oacc accumulates straight across all 4 experts (K = 1536 total).
// NO barriers (epilogue LDS transpose is wave-local).
__global__ __launch_bounds__(256, 3) void k2(
    const float* __restrict__ x, const uint8_t* __restrict__ w2f8,
    const float* __restrict__ b2, const float* __restrict__ scp,
    const float* __restrict__ gws, const uint8_t* __restrict__ hid,
    float* __restrict__ out, int c0)
{
  __shared__ __align__(16) float outl[192 * 65];   // 49920 B
  const int tid  = threadIdx.x;
  const int lane = tid & 63;
  const int wv   = tid >> 6;
  const int lq   = lane & 15;
  const int lg   = lane >> 4;
  const int lt   = blockIdx.x;
  const int tile = c0 * TPC + lt;
  const int b    = tile >> 8;
  const int n0   = (tile & 255) << 6;

  const uint8_t* w2t = w2f8 + (size_t)(wv * 48 + lq) * HIDD + 8 * lg;
  const uint8_t* hb[4];
  #pragma unroll
  for (int np = 0; np < 4; ++np)
    hb[np] = hid + ((size_t)(lt * 64 + 16 * np + lq)) * (4 * 384) + 8 * lg;

  f32x4 oacc[3][4];
  #pragma unroll
  for (int m = 0; m < 3; ++m)
    #pragma unroll
    for (int np = 0; np < 4; ++np)
      oacc[m][np] = (f32x4){0.f, 0.f, 0.f, 0.f};

  #pragma unroll 1
  for (int e = 0; e < EE; ++e){
    const uint8_t* w2p = w2t + (size_t)e * CC * HIDD;
    const uint32_t ho = (uint32_t)e * 384u;
    #pragma unroll
    for (int kk = 0; kk < 12; ++kk){
      u64 wfa[3], hfb[4];
      #pragma unroll
      for (int m = 0; m < 3; ++m)
        wfa[m] = *(const u64*)(w2p + (size_t)(16 * m) * HIDD + kk * 32);
      #pragma unroll
      for (int np = 0; np < 4; ++np)
        hfb[np] = *(const u64*)(hb[np] + ho + kk * 32);
      #pragma unroll
      for (int np = 0; np < 4; ++np)
        #pragma unroll
        for (int m = 0; m < 3; ++m)
          oacc[m][np] = mfma8(wfa[m], hfb[np], oacc[m][np]);
    }
  }

  // epilogue: wave-local LDS transpose -> coalesced bias + residual + store
  #pragma unroll
  for (int m = 0; m < 3; ++m)
    #pragma unroll
    for (int np = 0; np < 4; ++np){
      const int t  = 16 * np + lq;
      const int c0r = wv * 48 + 16 * m + 4 * lg;
      #pragma unroll
      for (int r = 0; r < 4; ++r)
        outl[(c0r + r) * 65 + t] = oacc[m][np][r];
    }
  // same-wave RAW on LDS: compiler inserts lgkmcnt; no cross-wave sharing here
  {
    const int t = lane;
    const float sc = scp[0];
    const f32x4 g4 = *(const f32x4*)(gws + ((size_t)lt * 64 + t) * 4);
    const float* xbt = x + (size_t)b * CC * NN + n0 + t;
    float* ob = out + (size_t)b * CC * NN + n0 + t;
    #pragma unroll 4
    for (int j = 0; j < 48; ++j){
      const int c = wv * 48 + j;
      const float o  = outl[c * 65 + t];
      const float bt = __builtin_fmaf(g4[0], b2[c],
                        __builtin_fmaf(g4[1], b2[CC + c],
                         __builtin_fmaf(g4[2], b2[2 * CC + c], g4[3] * b2[3 * CC + c])));
      const float xv = xbt[(size_t)c * NN];
      ob[(size_t)c * NN] = __builtin_fmaf(sc, o + bt, xv);
    }
  }
}

extern "C" void kernel_launch(void* const* d_in, const int* in_sizes, int n_in,
                              void* d_out, int out_size, void* d_ws, size_t ws_size,
                              hipStream_t stream){
  const float* x  = (const float*)d_in[0];
  const float* rw = (const float*)d_in[1];
  const float* rb = (const float*)d_in[2];
  const float* w1 = (const float*)d_in[3];
  const float* b1 = (const float*)d_in[4];
  const float* w2 = (const float*)d_in[5];
  const float* b2 = (const float*)d_in[6];
  const float* sc = (const float*)d_in[7];
  float* out = (float*)d_out;

  uint8_t* ws = (uint8_t*)d_ws;
  uint16_t* w1b  = (uint16_t*)(ws + WS_W1B);
  uint8_t*  w2f8 = ws + WS_W2F8;
  float*    gws  = (float*)(ws + WS_GATES);
  uint8_t*  hid  = ws + WS_HID;

  hipLaunchKernelGGL(kconv, dim3(1152), dim3(256), 0, stream, w1, w2, w1b, w2f8);
  for (int c0 = 0; c0 < NCHUNK; ++c0){
    hipLaunchKernelGGL(k1, dim3(TPC), dim3(256), 0, stream,
                       x, rw, rb, w1b, b1, gws, hid, c0);
    hipLaunchKernelGGL(k2, dim3(TPC), dim3(256), 0, stream,
                       x, w2f8, b2, sc, gws, hid, out, c0);
  }
}

// Round 9
// 343.434 us; speedup vs baseline: 1.8786x; 1.8786x over previous
//
#include <hip/hip_runtime.h>
#include <stdint.h>

typedef __attribute__((ext_vector_type(4))) float f32x4;
typedef __attribute__((ext_vector_type(8))) short s16x8;

#define CC   192
#define NN   16384
#define EE   4
#define HIDD 384

// LDS map (dynamic, 74752 B) -> 2 blocks/CU:
//  [0,     24576)  X tile [64 tok][192 ch] bf16, XOR-swizzled — resident whole kernel
//  [24576, 49152)  hid buf0 (router partials [24576,28672) pre-loop only)
//  [49152, 73728)  hid buf1
//  [73728, 74752)  gates [64 tok][4 e] f32
//  epilogue: outl [192 c][65 tok] f32 = 49920 B overlays X + h0
// Schedule: [GEMM2_i || GEMM1_{i+1}] -> gelu_{i+1} -> other hid buf -> ONE barrier.
// launch_bounds(256,2): 256-VGPR/wave budget. R7's identical schedule at (256,3)
// spilled (WRITE 98->187 MB); R8's k2 showed 68-VGPR kernels serialize on every
// load cluster (~1000 cyc each). Registers ARE the pipeline depth here.
#define OFF_H0   24576u
#define OFF_H1   49152u
#define OFF_PART 24576
#define OFF_GATE 73728
#define LDS_SZ   74752

__device__ __forceinline__ uint16_t bfbits(float f){
  uint32_t u = __builtin_bit_cast(uint32_t, f);
  u += 0x7FFFu + ((u >> 16) & 1u);
  return (uint16_t)(u >> 16);
}
__device__ __forceinline__ uint32_t pkbf(float lo, float hi){
  uint32_t ul = __builtin_bit_cast(uint32_t, lo);
  uint32_t uh = __builtin_bit_cast(uint32_t, hi);
  ul += 0x7FFFu + ((ul >> 16) & 1u);
  uh += 0x7FFFu + ((uh >> 16) & 1u);
  return (ul >> 16) | (uh & 0xFFFF0000u);
}
// tanh-form GELU, |err| <= ~3e-3 (threshold 0.109; measured absmax 0.031)
__device__ __forceinline__ float gelu_f(float v){
  float x2 = v * v;
  float z = v * __builtin_fmaf(x2, -0.1029432f, -2.3022082f);
  float e = __builtin_amdgcn_exp2f(z);
  return v * __builtin_amdgcn_rcpf(1.0f + e);
}
__device__ __forceinline__ f32x4 mfma16(s16x8 a, s16x8 b, f32x4 c){
  return __builtin_amdgcn_mfma_f32_16x16x32_bf16(a, b, c, 0, 0, 0);
}

// one K-step of GEMM1: A = fc1 rows (48 feat/wave), B = X tile (LDS)
__device__ __forceinline__ void g1_kk(const uint16_t* __restrict__ w1p,
                                      const unsigned char* S, const uint32_t rowb[4],
                                      uint32_t xsw, int lg, int kk, f32x4 (&acc)[3][4]){
  s16x8 wf[3], xk[4];
  #pragma unroll
  for (int m = 0; m < 3; ++m)
    wf[m] = *(const s16x8*)(w1p + (size_t)(16 * m) * CC + kk * 32);
  #pragma unroll
  for (int np = 0; np < 4; ++np)
    xk[np] = *(const s16x8*)(S + rowb[np] + (((uint32_t)(64 * kk + 16 * lg)) ^ xsw));
  #pragma unroll
  for (int np = 0; np < 4; ++np)
    #pragma unroll
    for (int m = 0; m < 3; ++m)
      acc[m][np] = mfma16(wf[m], xk[np], acc[m][np]);
}

// one K-step of GEMM2: A = fc2 rows, B = hid tile (LDS buffer hb)
__device__ __forceinline__ void g2_kk(const uint16_t* __restrict__ w2p,
                                      const unsigned char* S, uint32_t hb,
                                      const uint32_t rowb[4],
                                      uint32_t xsw, int lg, int kk, f32x4 (&acc)[3][4]){
  s16x8 wf[3], hf[4];
  #pragma unroll
  for (int m = 0; m < 3; ++m)
    wf[m] = *(const s16x8*)(w2p + (size_t)(16 * m) * HIDD + kk * 32);
  #pragma unroll
  for (int np = 0; np < 4; ++np)
    hf[np] = *(const s16x8*)(S + hb + rowb[np]
                             + (((uint32_t)(64 * kk + 16 * lg)) ^ xsw));
  #pragma unroll
  for (int np = 0; np < 4; ++np)
    #pragma unroll
    for (int m = 0; m < 3; ++m)
      acc[m][np] = mfma16(wf[m], hf[np], acc[m][np]);
}

// GELU*gate on a hacc tile -> hid LDS buffer hb (b64 writes)
__device__ __forceinline__ void gelu_store(unsigned char* S, uint32_t hb,
                                           const uint32_t rowb[4],
                                           uint32_t xsw, int wv, int lg,
                                           const float gt[4], const f32x4 (&acc)[3][4]){
  #pragma unroll
  for (int np = 0; np < 4; ++np){
    const uint32_t tb = hb + rowb[np];
    const float g = gt[np];
    #pragma unroll
    for (int m = 0; m < 3; ++m){
      const float v0 = gelu_f(acc[m][np][0]) * g;
      const float v1 = gelu_f(acc[m][np][1]) * g;
      const float v2 = gelu_f(acc[m][np][2]) * g;
      const float v3 = gelu_f(acc[m][np][3]) * g;
      uint2 p; p.x = pkbf(v0, v1); p.y = pkbf(v2, v3);
      *(uint2*)(S + tb + (((uint32_t)(96 * wv + 32 * m + 8 * lg)) ^ xsw)) = p;
    }
  }
}

extern "C" __global__ void kconv(const float* __restrict__ w1, const float* __restrict__ w2,
                                 uint16_t* __restrict__ w1b, uint16_t* __restrict__ w2b){
  int i = blockIdx.x * 256 + threadIdx.x;
  w1b[i] = bfbits(w1[i]);
  w2b[i] = bfbits(w2[i]);
}

// 1 block = 64 tokens, 256 threads = 4 waves; waves split the feature dim.
// A-operand = weights, B-operand = activations; D = [feature][token].
__global__ __launch_bounds__(256, 2) void kmoe(
    const float* __restrict__ x, const float* __restrict__ rw,
    const float* __restrict__ rb, const uint16_t* __restrict__ w1b,
    const float* __restrict__ b1, const uint16_t* __restrict__ w2b,
    const float* __restrict__ b2, const float* __restrict__ scp,
    float* __restrict__ out)
{
  extern __shared__ __align__(16) unsigned char S[];
  const int tid  = threadIdx.x;
  const int lane = tid & 63;
  const int wv   = tid >> 6;
  const int lq   = lane & 15;
  const int lg   = lane >> 4;
  const int tile = blockIdx.x;
  const int b    = tile >> 8;
  const int n0   = (tile & 255) << 6;
  const float* xb = x + (size_t)b * CC * NN;

  // ---- Phase 1: stage X tile (bf16, swizzled) + fp32 router partials
  {
    const int t = lane;
    const uint32_t rowbp = (uint32_t)t * 384u;
    const uint32_t sw    = ((uint32_t)(t & 7)) << 4;
    float a0 = 0.f, a1 = 0.f, a2 = 0.f, a3 = 0.f;
    #pragma unroll 8
    for (int j = 0; j < 48; j += 2){
      const int c = wv * 48 + j;
      const float v0 = xb[(size_t)c * NN + n0 + t];
      const float v1 = xb[(size_t)(c + 1) * NN + n0 + t];
      a0 = __builtin_fmaf(v1, rw[c + 1],          __builtin_fmaf(v0, rw[c],          a0));
      a1 = __builtin_fmaf(v1, rw[CC + c + 1],     __builtin_fmaf(v0, rw[CC + c],     a1));
      a2 = __builtin_fmaf(v1, rw[2 * CC + c + 1], __builtin_fmaf(v0, rw[2 * CC + c], a2));
      a3 = __builtin_fmaf(v1, rw[3 * CC + c + 1], __builtin_fmaf(v0, rw[3 * CC + c], a3));
      *(uint32_t*)(S + rowbp + (((uint32_t)(2 * c)) ^ sw)) = pkbf(v0, v1);
    }
    float* pl = (float*)(S + OFF_PART);
    pl[(wv * 4 + 0) * 64 + t] = a0;
    pl[(wv * 4 + 1) * 64 + t] = a1;
    pl[(wv * 4 + 2) * 64 + t] = a2;
    pl[(wv * 4 + 3) * 64 + t] = a3;
  }
  __syncthreads();

  // ---- Phase 2 (tid<64): router finalize -> gates
  if (tid < 64){
    const int t = tid;
    const float* pl = (const float*)(S + OFF_PART);
    float l0 = rb[0], l1 = rb[1], l2 = rb[2], l3 = rb[3];
    #pragma unroll
    for (int cg = 0; cg < 4; ++cg){
      l0 += pl[(cg * 4 + 0) * 64 + t];
      l1 += pl[(cg * 4 + 1) * 64 + t];
      l2 += pl[(cg * 4 + 2) * 64 + t];
      l3 += pl[(cg * 4 + 3) * 64 + t];
    }
    int i1 = 0; float v1 = l0;
    if (l1 > v1){ v1 = l1; i1 = 1; }
    if (l2 > v1){ v1 = l2; i1 = 2; }
    if (l3 > v1){ v1 = l3; i1 = 3; }
    float v2 = -3.0e38f; int i2 = 0;
    if (i1 != 0){ v2 = l0; i2 = 0; }
    if (i1 != 1 && l1 > v2){ v2 = l1; i2 = 1; }
    if (i1 != 2 && l2 > v2){ v2 = l2; i2 = 2; }
    if (i1 != 3 && l3 > v2){ v2 = l3; i2 = 3; }
    const float ex = __expf(v2 - v1);
    const float ga = 1.0f / (1.0f + ex);
    const float gb = ex * ga;
    float* glw = (float*)(S + OFF_GATE);
    glw[t * 4 + 0] = (i1 == 0) ? ga : ((i2 == 0) ? gb : 0.0f);
    glw[t * 4 + 1] = (i1 == 1) ? ga : ((i2 == 1) ? gb : 0.0f);
    glw[t * 4 + 2] = (i1 == 2) ? ga : ((i2 == 2) ? gb : 0.0f);
    glw[t * 4 + 3] = (i1 == 3) ? ga : ((i2 == 3) ? gb : 0.0f);
  }
  __syncthreads();   // X + gates settled; partials region free for hid buf0

  const float* gl = (const float*)(S + OFF_GATE);
  const uint16_t* w1t = w1b + (size_t)(wv * 48 + lq) * CC   + 8 * lg;
  const uint16_t* w2t = w2b + (size_t)(wv * 48 + lq) * HIDD + 8 * lg;
  const uint32_t xsw = ((uint32_t)(lq & 7)) << 4;
  uint32_t rowb[4];
  #pragma unroll
  for (int np = 0; np < 4; ++np) rowb[np] = (uint32_t)(16 * np + lq) * 384u;

  f32x4 oacc[3][4];
  #pragma unroll
  for (int m = 0; m < 3; ++m)
    #pragma unroll
    for (int np = 0; np < 4; ++np)
      oacc[m][np] = (f32x4){0.f, 0.f, 0.f, 0.f};

  // ---- Prologue: GEMM1(0) -> gelu(0) -> h0 -> barrier
  {
    f32x4 hacc[3][4];
    #pragma unroll
    for (int m = 0; m < 3; ++m){
      const f32x4 bv = *(const f32x4*)(b1 + wv * 48 + 16 * m + 4 * lg);
      #pragma unroll
      for (int np = 0; np < 4; ++np) hacc[m][np] = bv;
    }
    __builtin_amdgcn_s_setprio(1);
    #pragma unroll
    for (int kk = 0; kk < 6; ++kk)
      g1_kk(w1t, S, rowb, xsw, lg, kk, hacc);
    __builtin_amdgcn_s_setprio(0);
    float gt[4];
    #pragma unroll
    for (int np = 0; np < 4; ++np) gt[np] = gl[(16 * np + lq) * 4 + 0];
    gelu_store(S, OFF_H0, rowb, xsw, wv, lg, gt, hacc);
  }
  __syncthreads();   // h(0) visible

  // ---- Main loop i=0..6: [G2_i(read hb_r) || G1_{i+1}] -> gelu_{i+1} -> hb_w -> bar
  #pragma unroll 1
  for (int i = 0; i < 7; ++i){
    const uint32_t hb_r = (i & 1) ? OFF_H1 : OFF_H0;
    const uint32_t hb_w = (i & 1) ? OFF_H0 : OFF_H1;
    const int e2 = i >> 1,       ch2 = i & 1;
    const int e1 = (i + 1) >> 1, ch1 = (i + 1) & 1;
    const uint16_t* w2p = w2t + (size_t)(e2 * CC) * HIDD + ch2 * 192;
    const uint16_t* w1p = w1t + (size_t)(e1 * HIDD + ch1 * 192) * CC;
    f32x4 hacc[3][4];
    #pragma unroll
    for (int m = 0; m < 3; ++m){
      const f32x4 bv = *(const f32x4*)(b1 + e1 * HIDD + ch1 * 192 + wv * 48 + 16 * m + 4 * lg);
      #pragma unroll
      for (int np = 0; np < 4; ++np) hacc[m][np] = bv;
    }
    __builtin_amdgcn_s_setprio(1);
    #pragma unroll
    for (int kk = 0; kk < 6; ++kk){
      g2_kk(w2p, S, hb_r, rowb, xsw, lg, kk, oacc);   // consumes hid_i
      g1_kk(w1p, S, rowb, xsw, lg, kk, hacc);         // produces hacc_{i+1} (regs)
    }
    __builtin_amdgcn_s_setprio(0);
    float gt[4];
    #pragma unroll
    for (int np = 0; np < 4; ++np) gt[np] = gl[(16 * np + lq) * 4 + e1];
    gelu_store(S, hb_w, rowb, xsw, wv, lg, gt, hacc);  // writes OTHER buffer
    __syncthreads();   // hid_{i+1} visible; also fences next iter's buffer swap
  }

  // ---- Tail: GEMM2(7) reads h(7) = buf1
  {
    const uint16_t* w2p = w2t + (size_t)(3 * CC) * HIDD + 192;
    __builtin_amdgcn_s_setprio(1);
    #pragma unroll
    for (int kk = 0; kk < 6; ++kk)
      g2_kk(w2p, S, OFF_H1, rowb, xsw, lg, kk, oacc);
    __builtin_amdgcn_s_setprio(0);
  }

  // ---- Epilogue: gates -> regs, oacc -> LDS transpose [c][65], coalesced store
  const f32x4 g4 = *(const f32x4*)(S + OFF_GATE + lane * 16);
  __syncthreads();   // all hid reads done; outl overlays X + h0
  {
    float* outl = (float*)S;
    #pragma unroll
    for (int m = 0; m < 3; ++m)
      #pragma unroll
      for (int np = 0; np < 4; ++np){
        const int t  = 16 * np + lq;
        const int c0 = wv * 48 + 16 * m + 4 * lg;
        #pragma unroll
        for (int r = 0; r < 4; ++r)
          outl[(c0 + r) * 65 + t] = oacc[m][np][r];
      }
  }
  __syncthreads();
  {
    const int t = lane;
    const float sc = scp[0];
    const float* outl = (const float*)S;
    const float* xbt = xb + n0 + t;
    float* ob = out + (size_t)b * CC * NN + n0 + t;
    #pragma unroll 4
    for (int j = 0; j < 48; ++j){
      const int c = wv * 48 + j;
      const float o  = outl[c * 65 + t];
      const float bt = __builtin_fmaf(g4[0], b2[c],
                        __builtin_fmaf(g4[1], b2[CC + c],
                         __builtin_fmaf(g4[2], b2[2 * CC + c], g4[3] * b2[3 * CC + c])));
      const float xv = xbt[(size_t)c * NN];
      ob[(size_t)c * NN] = __builtin_fmaf(sc, o + bt, xv);
    }
  }
}

extern "C" void kernel_launch(void* const* d_in, const int* in_sizes, int n_in,
                              void* d_out, int out_size, void* d_ws, size_t ws_size,
                              hipStream_t stream){
  const float* x  = (const float*)d_in[0];
  const float* rw = (const float*)d_in[1];
  const float* rb = (const float*)d_in[2];
  const float* w1 = (const float*)d_in[3];
  const float* b1 = (const float*)d_in[4];
  const float* w2 = (const float*)d_in[5];
  const float* b2 = (const float*)d_in[6];
  const float* sc = (const float*)d_in[7];
  float* out = (float*)d_out;
  uint16_t* w1b = (uint16_t*)d_ws;
  uint16_t* w2b = w1b + 294912;

  hipLaunchKernelGGL(kconv, dim3(1152), dim3(256), 0, stream, w1, w2, w1b, w2b);
  hipLaunchKernelGGL(kmoe,  dim3(2048), dim3(256), LDS_SZ, stream,
                     x, rw, rb, w1b, b1, w2b, b2, sc, out);
}